// Round 1
// baseline (587.853 us; speedup 1.0000x reference)
//
#include <hip/hip_runtime.h>
#include <math.h>

#define NS_ 50000
#define NW_ 50000
#define IN_DIM_ 128
#define OUT_DIM_ 64

__device__ inline void atomicMaxFloat(float* addr, float val) {
    // works for all finite floats + -inf init:
    // positives: int compare == float compare; negatives: unsigned min == float max
    if (val >= 0.0f) {
        atomicMax((int*)addr, __float_as_int(val));
    } else {
        atomicMin((unsigned int*)addr, __float_as_uint(val));
    }
}

__device__ inline float leaky01(float x) { return x > 0.0f ? x : 0.01f * x; }

__global__ __launch_bounds__(256) void init_kernel(float* __restrict__ m,
                                                   float* __restrict__ den, int n) {
    int i = blockIdx.x * 256 + threadIdx.x;
    if (i < n) {
        m[i] = -INFINITY;
        den[i] = 0.0f;
    }
}

// z = h @ W_fc  (NS x 128 @ 128 x 64), fused t[row] = sum_c z[row][c] * w_attn[c]
// block = 256 threads = 4 row-slots x 64 cols; W_fc staged in LDS (32 KB)
__global__ __launch_bounds__(256) void fc_kernel(const float* __restrict__ h,
                                                 const float* __restrict__ Wfc,
                                                 const float* __restrict__ w_attn,
                                                 float* __restrict__ z,
                                                 float* __restrict__ t,
                                                 int rows_per_block) {
    __shared__ float Ws[IN_DIM_][OUT_DIM_];
    int tid = threadIdx.x;
    for (int i = tid; i < IN_DIM_ * OUT_DIM_; i += 256) ((float*)Ws)[i] = Wfc[i];
    __syncthreads();

    int lane = tid & 63;   // output column
    int slot = tid >> 6;   // row slot within block (wave id)
    float wa = w_attn[lane];  // w_attn[:64, 0]

    int row0 = blockIdx.x * rows_per_block;
    int row_end = row0 + rows_per_block;
    if (row_end > NS_) row_end = NS_;

    for (int r = row0 + slot; r < row_end; r += 4) {
        const float4* hrow = (const float4*)(h + (size_t)r * IN_DIM_);
        float acc = 0.0f;
#pragma unroll
        for (int k4 = 0; k4 < IN_DIM_ / 4; ++k4) {
            float4 hv = hrow[k4];  // wave-uniform broadcast load
            acc = fmaf(hv.x, Ws[k4 * 4 + 0][lane], acc);
            acc = fmaf(hv.y, Ws[k4 * 4 + 1][lane], acc);
            acc = fmaf(hv.z, Ws[k4 * 4 + 2][lane], acc);
            acc = fmaf(hv.w, Ws[k4 * 4 + 3][lane], acc);
        }
        z[(size_t)r * OUT_DIM_ + lane] = acc;

        // t[r] = sum over 64 cols of acc * wa  (whole wave = one row)
        float tv = acc * wa;
#pragma unroll
        for (int off = 32; off > 0; off >>= 1) tv += __shfl_down(tv, off, 64);
        if (lane == 0) t[r] = tv;
    }
}

// per-edge segment max of e = weight * leaky_relu(t[src]) into m[dst]
__global__ __launch_bounds__(256) void edge_max_kernel(const float* __restrict__ weight,
                                                       const int* __restrict__ src,
                                                       const int* __restrict__ dst,
                                                       const float* __restrict__ t,
                                                       float* __restrict__ m, int E) {
    int e = blockIdx.x * 256 + threadIdx.x;
    if (e >= E) return;
    float ev = weight[e] * leaky01(t[src[e]]);
    atomicMaxFloat(&m[dst[e]], ev);
}

// per-edge: den[dst] += exp(e - m[dst])
__global__ __launch_bounds__(256) void edge_den_kernel(const float* __restrict__ weight,
                                                       const int* __restrict__ src,
                                                       const int* __restrict__ dst,
                                                       const float* __restrict__ t,
                                                       const float* __restrict__ m,
                                                       float* __restrict__ den, int E) {
    int e = blockIdx.x * 256 + threadIdx.x;
    if (e >= E) return;
    int d = dst[e];
    float ev = weight[e] * leaky01(t[src[e]]);
    float ex = expf(ev - m[d]);
    atomicAdd(&den[d], ex);
}

// one wave per edge, lane = output dim: out[dst][lane] += alpha * z[src][lane]
__global__ __launch_bounds__(256) void edge_accum_kernel(const float* __restrict__ weight,
                                                         const int* __restrict__ src,
                                                         const int* __restrict__ dst,
                                                         const float* __restrict__ t,
                                                         const float* __restrict__ m,
                                                         const float* __restrict__ den,
                                                         const float* __restrict__ z,
                                                         float* __restrict__ out, int E) {
    unsigned int gid = blockIdx.x * 256u + threadIdx.x;
    int e = (int)(gid >> 6);
    if (e >= E) return;
    int lane = (int)(gid & 63u);
    int s = src[e];  // wave-uniform
    int d = dst[e];
    float ev = weight[e] * leaky01(t[s]);
    float ex = expf(ev - m[d]);
    float dn = den[d];
    float alpha = ex / (dn == 0.0f ? 1.0f : dn);
    atomicAdd(&out[(size_t)d * OUT_DIM_ + lane], alpha * z[(size_t)s * OUT_DIM_ + lane]);
}

extern "C" void kernel_launch(void* const* d_in, const int* in_sizes, int n_in,
                              void* d_out, int out_size, void* d_ws, size_t ws_size,
                              hipStream_t stream) {
    const float* h      = (const float*)d_in[0];
    const float* Wfc    = (const float*)d_in[1];
    const float* w_attn = (const float*)d_in[2];
    const float* weight = (const float*)d_in[3];
    const int*   src    = (const int*)d_in[4];
    const int*   dst    = (const int*)d_in[5];
    int E = in_sizes[3];
    float* out = (float*)d_out;

    // workspace layout: t[NS] | m[NW] | den[NW] | z[NS*64]
    float* t   = (float*)d_ws;
    float* m   = t + NS_;
    float* den = m + NW_;
    float* z   = den + NW_;

    // out accumulates atomically -> zero it every call (harness doesn't re-poison)
    hipMemsetAsync(d_out, 0, (size_t)out_size * sizeof(float), stream);

    init_kernel<<<(NW_ + 255) / 256, 256, 0, stream>>>(m, den, NW_);

    const int rows_per_block = 32;
    fc_kernel<<<(NS_ + rows_per_block - 1) / rows_per_block, 256, 0, stream>>>(
        h, Wfc, w_attn, z, t, rows_per_block);

    int eblocks = (E + 255) / 256;
    edge_max_kernel<<<eblocks, 256, 0, stream>>>(weight, src, dst, t, m, E);
    edge_den_kernel<<<eblocks, 256, 0, stream>>>(weight, src, dst, t, m, den, E);

    // E * 64 lanes, 4 edges per 256-thread block
    long long total = (long long)E * OUT_DIM_;
    int ablocks = (int)((total + 255) / 256);
    edge_accum_kernel<<<ablocks, 256, 0, stream>>>(weight, src, dst, t, m, den, z, out, E);
}

// Round 2
// 524.051 us; speedup vs baseline: 1.1217x; 1.1217x over previous
//
#include <hip/hip_runtime.h>
#include <math.h>

#define NS_ 50000
#define NW_ 50000
#define IN_DIM_ 128
#define OUT_DIM_ 64

__device__ inline float leaky01(float x) { return x > 0.0f ? x : 0.01f * x; }

// z = h @ W_fc  (NS x 128 @ 128 x 64), fused t[row] = sum_c z[row][c] * w_attn[c]
// block = 256 threads = 4 row-slots x 64 cols; W_fc staged in LDS (32 KB)
__global__ __launch_bounds__(256) void fc_kernel(const float* __restrict__ h,
                                                 const float* __restrict__ Wfc,
                                                 const float* __restrict__ w_attn,
                                                 float* __restrict__ z,
                                                 float* __restrict__ t,
                                                 int rows_per_block) {
    __shared__ float Ws[IN_DIM_][OUT_DIM_];
    int tid = threadIdx.x;
    for (int i = tid; i < IN_DIM_ * OUT_DIM_; i += 256) ((float*)Ws)[i] = Wfc[i];
    __syncthreads();

    int lane = tid & 63;   // output column
    int slot = tid >> 6;   // row slot within block (wave id)
    float wa = w_attn[lane];  // w_attn[:64, 0]

    int row0 = blockIdx.x * rows_per_block;
    int row_end = row0 + rows_per_block;
    if (row_end > NS_) row_end = NS_;

    for (int r = row0 + slot; r < row_end; r += 4) {
        const float4* hrow = (const float4*)(h + (size_t)r * IN_DIM_);
        float acc = 0.0f;
#pragma unroll
        for (int k4 = 0; k4 < IN_DIM_ / 4; ++k4) {
            float4 hv = hrow[k4];  // wave-uniform broadcast load
            acc = fmaf(hv.x, Ws[k4 * 4 + 0][lane], acc);
            acc = fmaf(hv.y, Ws[k4 * 4 + 1][lane], acc);
            acc = fmaf(hv.z, Ws[k4 * 4 + 2][lane], acc);
            acc = fmaf(hv.w, Ws[k4 * 4 + 3][lane], acc);
        }
        z[(size_t)r * OUT_DIM_ + lane] = acc;

        // t[r] = sum over 64 cols of acc * wa  (whole wave = one row)
        float tv = acc * wa;
#pragma unroll
        for (int off = 32; off > 0; off >>= 1) tv += __shfl_down(tv, off, 64);
        if (lane == 0) t[r] = tv;
    }
}

// histogram of dst
__global__ __launch_bounds__(256) void hist_kernel(const int* __restrict__ dst,
                                                   int* __restrict__ count, int E) {
    int e = blockIdx.x * 256 + threadIdx.x;
    if (e < E) atomicAdd(&count[dst[e]], 1);
}

// single-block exclusive scan over count[0..n) -> start[0..n], copy to cursor
__global__ __launch_bounds__(1024) void scan_kernel(const int* __restrict__ count,
                                                    int* __restrict__ start,
                                                    int* __restrict__ cursor, int n) {
    __shared__ int sums[1024];
    int t = threadIdx.x;
    int chunk = (n + 1023) >> 10;
    int lo = t * chunk;
    int hi = lo + chunk; if (hi > n) hi = n;
    int s = 0;
    for (int i = lo; i < hi; ++i) s += count[i];
    sums[t] = s;
    __syncthreads();
    for (int off = 1; off < 1024; off <<= 1) {
        int v = (t >= off) ? sums[t - off] : 0;
        __syncthreads();
        sums[t] += v;
        __syncthreads();
    }
    int run = (t == 0) ? 0 : sums[t - 1];
    for (int i = lo; i < hi; ++i) {
        start[i] = run;
        cursor[i] = run;
        run += count[i];
    }
    if (t == 1023) start[n] = run;
}

// scatter edges into CSR order: eperm[pos] = e-value, sperm[pos] = src
__global__ __launch_bounds__(256) void scatter_kernel(const float* __restrict__ weight,
                                                      const int* __restrict__ src,
                                                      const int* __restrict__ dst,
                                                      const float* __restrict__ t,
                                                      int* __restrict__ cursor,
                                                      float* __restrict__ eperm,
                                                      int* __restrict__ sperm, int E) {
    int e = blockIdx.x * 256 + threadIdx.x;
    if (e >= E) return;
    int s = src[e];
    int d = dst[e];
    float ev = weight[e] * leaky01(t[s]);
    int pos = atomicAdd(&cursor[d], 1);
    eperm[pos] = ev;
    sperm[pos] = s;
}

// one wave per dst: in-register softmax over its edge list + weighted gather-sum of z
__global__ __launch_bounds__(256) void aggregate_kernel(const int* __restrict__ start,
                                                        const float* __restrict__ eperm,
                                                        const int* __restrict__ sperm,
                                                        const float* __restrict__ z,
                                                        float* __restrict__ out, int nw) {
    int wid = (int)((blockIdx.x * 256u + threadIdx.x) >> 6);
    int lane = threadIdx.x & 63;
    if (wid >= nw) return;
    int s0 = start[wid];
    int n = start[wid + 1] - s0;
    float acc = 0.0f;
    if (n > 0) {
        // max over edge scores (lane-parallel + shuffle reduce)
        float mx = -INFINITY;
        for (int i = lane; i < n; i += 64) mx = fmaxf(mx, eperm[s0 + i]);
#pragma unroll
        for (int off = 32; off > 0; off >>= 1) mx = fmaxf(mx, __shfl_xor(mx, off, 64));
        // sum of exp
        float den = 0.0f;
        for (int i = lane; i < n; i += 64) den += __expf(eperm[s0 + i] - mx);
#pragma unroll
        for (int off = 32; off > 0; off >>= 1) den += __shfl_xor(den, off, 64);
        float inv_den = 1.0f / den;  // den > 0 guaranteed (n > 0, exp > 0)
        // weighted accumulate: lane = output dim, serial over edges
        for (int i = 0; i < n; ++i) {
            float ev = eperm[s0 + i];   // wave-uniform broadcast
            int s = sperm[s0 + i];      // wave-uniform broadcast
            float alpha = __expf(ev - mx) * inv_den;
            acc = fmaf(alpha, z[(size_t)s * OUT_DIM_ + lane], acc);
        }
    }
    out[(size_t)wid * OUT_DIM_ + lane] = acc;
}

extern "C" void kernel_launch(void* const* d_in, const int* in_sizes, int n_in,
                              void* d_out, int out_size, void* d_ws, size_t ws_size,
                              hipStream_t stream) {
    const float* h      = (const float*)d_in[0];
    const float* Wfc    = (const float*)d_in[1];
    const float* w_attn = (const float*)d_in[2];
    const float* weight = (const float*)d_in[3];
    const int*   src    = (const int*)d_in[4];
    const int*   dst    = (const int*)d_in[5];
    int E = in_sizes[3];
    float* out = (float*)d_out;

    // workspace layout
    float* t      = (float*)d_ws;            // NS
    float* z      = t + NS_;                 // NS*64
    int*   count  = (int*)(z + (size_t)NS_ * OUT_DIM_);  // NW
    int*   start  = count + NW_;             // NW+1
    int*   cursor = start + NW_ + 1;         // NW
    float* eperm  = (float*)(cursor + NW_);  // E
    int*   sperm  = (int*)(eperm + E);       // E

    hipMemsetAsync(count, 0, (size_t)NW_ * sizeof(int), stream);

    const int rows_per_block = 32;
    fc_kernel<<<(NS_ + rows_per_block - 1) / rows_per_block, 256, 0, stream>>>(
        h, Wfc, w_attn, z, t, rows_per_block);

    int eblocks = (E + 255) / 256;
    hist_kernel<<<eblocks, 256, 0, stream>>>(dst, count, E);
    scan_kernel<<<1, 1024, 0, stream>>>(count, start, cursor, NW_);
    scatter_kernel<<<eblocks, 256, 0, stream>>>(weight, src, dst, t, cursor, eperm, sperm, E);

    // one wave per dst, 4 waves per block
    int ablocks = (NW_ + 3) / 4;
    aggregate_kernel<<<ablocks, 256, 0, stream>>>(start, eperm, sperm, z, out, NW_);
}

// Round 3
// 381.931 us; speedup vs baseline: 1.5392x; 1.3721x over previous
//
#include <hip/hip_runtime.h>
#include <math.h>

#define NS_ 50000
#define NW_ 50000
#define IN_DIM_ 128
#define OUT_DIM_ 64

__device__ inline float leaky01(float x) { return x > 0.0f ? x : 0.01f * x; }

// z = h @ W_fc  (NS x 128 @ 128 x 64), fused t[row] = sum_c z[row][c] * w_attn[c]
__global__ __launch_bounds__(256) void fc_kernel(const float* __restrict__ h,
                                                 const float* __restrict__ Wfc,
                                                 const float* __restrict__ w_attn,
                                                 float* __restrict__ z,
                                                 float* __restrict__ t,
                                                 int rows_per_block) {
    __shared__ float Ws[IN_DIM_][OUT_DIM_];
    int tid = threadIdx.x;
    for (int i = tid; i < IN_DIM_ * OUT_DIM_; i += 256) ((float*)Ws)[i] = Wfc[i];
    __syncthreads();

    int lane = tid & 63;
    int slot = tid >> 6;
    float wa = w_attn[lane];

    int row0 = blockIdx.x * rows_per_block;
    int row_end = row0 + rows_per_block;
    if (row_end > NS_) row_end = NS_;

    for (int r = row0 + slot; r < row_end; r += 4) {
        const float4* hrow = (const float4*)(h + (size_t)r * IN_DIM_);
        float acc = 0.0f;
#pragma unroll
        for (int k4 = 0; k4 < IN_DIM_ / 4; ++k4) {
            float4 hv = hrow[k4];
            acc = fmaf(hv.x, Ws[k4 * 4 + 0][lane], acc);
            acc = fmaf(hv.y, Ws[k4 * 4 + 1][lane], acc);
            acc = fmaf(hv.z, Ws[k4 * 4 + 2][lane], acc);
            acc = fmaf(hv.w, Ws[k4 * 4 + 3][lane], acc);
        }
        z[(size_t)r * OUT_DIM_ + lane] = acc;

        float tv = acc * wa;
#pragma unroll
        for (int off = 32; off > 0; off >>= 1) tv += __shfl_down(tv, off, 64);
        if (lane == 0) t[r] = tv;
    }
}

// histogram of dst (4 edges/thread, vectorized)
__global__ __launch_bounds__(256) void hist_kernel(const int* __restrict__ dst,
                                                   int* __restrict__ count, int E) {
    int i = blockIdx.x * 256 + threadIdx.x;
    int base = i * 4;
    if (base + 3 < E) {
        int4 d = *(const int4*)(dst + base);
        atomicAdd(&count[d.x], 1);
        atomicAdd(&count[d.y], 1);
        atomicAdd(&count[d.z], 1);
        atomicAdd(&count[d.w], 1);
    } else {
        for (int k = base; k < E; ++k) atomicAdd(&count[dst[k]], 1);
    }
}

// single-block exclusive scan over count[0..n) -> start[0..n)
__global__ __launch_bounds__(1024) void scan_kernel(const int* __restrict__ count,
                                                    int* __restrict__ start, int n) {
    __shared__ int sums[1024];
    int t = threadIdx.x;
    int chunk = (n + 1023) >> 10;
    int lo = t * chunk;
    int hi = lo + chunk; if (hi > n) hi = n;
    int s = 0;
    for (int i = lo; i < hi; ++i) s += count[i];
    sums[t] = s;
    __syncthreads();
    for (int off = 1; off < 1024; off <<= 1) {
        int v = (t >= off) ? sums[t - off] : 0;
        __syncthreads();
        sums[t] += v;
        __syncthreads();
    }
    int run = (t == 0) ? 0 : sums[t - 1];
    for (int i = lo; i < hi; ++i) {
        start[i] = run;
        run += count[i];
    }
}

// scatter edges into CSR order: edata[pos] = (ev bits, src); bumps start[] (post: start = end)
__global__ __launch_bounds__(256) void scatter_kernel(const float* __restrict__ weight,
                                                      const int* __restrict__ src,
                                                      const int* __restrict__ dst,
                                                      const float* __restrict__ t,
                                                      int* __restrict__ start,
                                                      int2* __restrict__ edata, int E) {
    int e = blockIdx.x * 256 + threadIdx.x;
    if (e >= E) return;
    int s = src[e];
    int d = dst[e];
    float ev = weight[e] * leaky01(t[s]);
    int pos = atomicAdd(&start[d], 1);
    edata[pos] = make_int2(__float_as_int(ev), s);
}

// one wave per dst: coalesced edge-list load, per-lane alpha, shfl-broadcast inner loop
__global__ __launch_bounds__(256) void aggregate_kernel(const int* __restrict__ start_end,
                                                        const int* __restrict__ count,
                                                        const int2* __restrict__ edata,
                                                        const float* __restrict__ z,
                                                        float* __restrict__ out, int nw) {
    int wid = (int)((blockIdx.x * 256u + threadIdx.x) >> 6);
    int lane = threadIdx.x & 63;
    if (wid >= nw) return;
    int n = count[wid];
    int s0 = start_end[wid] - n;  // scatter advanced start[] by n

    float acc0 = 0.0f, acc1 = 0.0f, acc2 = 0.0f, acc3 = 0.0f;

    if (n > 0 && n <= 64) {
        // fast path: whole edge list in one coalesced 8B/lane load
        int2 ed = (lane < n) ? edata[s0 + lane] : make_int2(0xff800000, 0);  // -inf
        float ev = __int_as_float(ed.x);
        int s = ed.y;
        float mx = ev;
#pragma unroll
        for (int off = 32; off > 0; off >>= 1) mx = fmaxf(mx, __shfl_xor(mx, off, 64));
        float ex = (lane < n) ? __expf(ev - mx) : 0.0f;
        float den = ex;
#pragma unroll
        for (int off = 32; off > 0; off >>= 1) den += __shfl_xor(den, off, 64);
        float alpha = ex * (1.0f / den);

        int j = 0;
        for (; j + 4 <= n; j += 4) {
            float a0 = __shfl(alpha, j, 64);     int t0 = __shfl(s, j, 64);
            float a1 = __shfl(alpha, j + 1, 64); int t1 = __shfl(s, j + 1, 64);
            float a2 = __shfl(alpha, j + 2, 64); int t2 = __shfl(s, j + 2, 64);
            float a3 = __shfl(alpha, j + 3, 64); int t3 = __shfl(s, j + 3, 64);
            acc0 = fmaf(a0, z[(size_t)t0 * OUT_DIM_ + lane], acc0);
            acc1 = fmaf(a1, z[(size_t)t1 * OUT_DIM_ + lane], acc1);
            acc2 = fmaf(a2, z[(size_t)t2 * OUT_DIM_ + lane], acc2);
            acc3 = fmaf(a3, z[(size_t)t3 * OUT_DIM_ + lane], acc3);
        }
        for (; j < n; ++j) {
            float a = __shfl(alpha, j, 64); int ss = __shfl(s, j, 64);
            acc0 = fmaf(a, z[(size_t)ss * OUT_DIM_ + lane], acc0);
        }
    } else if (n > 64) {
        // generic chunked path (rare: Poisson(32) tail)
        float mx = -INFINITY;
        for (int base = 0; base < n; base += 64) {
            int i = base + lane;
            if (i < n) mx = fmaxf(mx, __int_as_float(edata[s0 + i].x));
        }
#pragma unroll
        for (int off = 32; off > 0; off >>= 1) mx = fmaxf(mx, __shfl_xor(mx, off, 64));
        float den = 0.0f;
        for (int base = 0; base < n; base += 64) {
            int i = base + lane;
            if (i < n) den += __expf(__int_as_float(edata[s0 + i].x) - mx);
        }
#pragma unroll
        for (int off = 32; off > 0; off >>= 1) den += __shfl_xor(den, off, 64);
        float inv = 1.0f / den;
        for (int base = 0; base < n; base += 64) {
            int cn = n - base; if (cn > 64) cn = 64;
            int2 ed = (lane < cn) ? edata[s0 + base + lane] : make_int2(0, 0);
            float alpha = (lane < cn) ? __expf(__int_as_float(ed.x) - mx) * inv : 0.0f;
            int s = ed.y;
            for (int j = 0; j < cn; ++j) {
                float a = __shfl(alpha, j, 64); int ss = __shfl(s, j, 64);
                acc0 = fmaf(a, z[(size_t)ss * OUT_DIM_ + lane], acc0);
            }
        }
    }
    out[(size_t)wid * OUT_DIM_ + lane] = acc0 + acc1 + acc2 + acc3;
}

extern "C" void kernel_launch(void* const* d_in, const int* in_sizes, int n_in,
                              void* d_out, int out_size, void* d_ws, size_t ws_size,
                              hipStream_t stream) {
    const float* h      = (const float*)d_in[0];
    const float* Wfc    = (const float*)d_in[1];
    const float* w_attn = (const float*)d_in[2];
    const float* weight = (const float*)d_in[3];
    const int*   src    = (const int*)d_in[4];
    const int*   dst    = (const int*)d_in[5];
    int E = in_sizes[3];
    float* out = (float*)d_out;

    // workspace layout (8B alignment for edata via NW_+2 pad on start)
    float* t     = (float*)d_ws;                       // NS
    float* z     = t + NS_;                            // NS*64
    int*   count = (int*)(z + (size_t)NS_ * OUT_DIM_); // NW
    int*   start = count + NW_;                        // NW+2 (pad)
    int2*  edata = (int2*)(start + NW_ + 2);           // E

    hipMemsetAsync(count, 0, (size_t)NW_ * sizeof(int), stream);

    const int rows_per_block = 32;
    fc_kernel<<<(NS_ + rows_per_block - 1) / rows_per_block, 256, 0, stream>>>(
        h, Wfc, w_attn, z, t, rows_per_block);

    int hblocks = (E / 4 + 255) / 256 + 1;
    hist_kernel<<<hblocks, 256, 0, stream>>>(dst, count, E);
    scan_kernel<<<1, 1024, 0, stream>>>(count, start, NW_);

    int eblocks = (E + 255) / 256;
    scatter_kernel<<<eblocks, 256, 0, stream>>>(weight, src, dst, t, start, edata, E);

    int ablocks = (NW_ + 3) / 4;
    aggregate_kernel<<<ablocks, 256, 0, stream>>>(start, count, edata, z, out, NW_);
}

// Round 4
// 175.924 us; speedup vs baseline: 3.3415x; 2.1710x over previous
//
#include <hip/hip_runtime.h>
#include <hip/hip_fp16.h>
#include <math.h>

#define NS_ 50000
#define NW_ 50000
#define IN_DIM_ 128
#define OUT_DIM_ 64

#define NSLAB 256          // partition slabs (blocks)
#define NB 782             // buckets = ceil(NW/64), bucket = dst >> 6
#define NBP 783            // offs row stride (NB + 1 total column)
#define CAP 2816           // LDS edge capacity per bucket (mean 2048, +17 sigma)

__device__ inline float leaky01(float x) { return x > 0.0f ? x : 0.01f * x; }

// z = h @ W_fc (fp16 out), fused t[row] = sum_c z[row][c] * w_attn[c]
__global__ __launch_bounds__(256) void fc_kernel(const float* __restrict__ h,
                                                 const float* __restrict__ Wfc,
                                                 const float* __restrict__ w_attn,
                                                 __half* __restrict__ z16,
                                                 float* __restrict__ t,
                                                 int rows_per_block) {
    __shared__ float Ws[IN_DIM_][OUT_DIM_];
    int tid = threadIdx.x;
    for (int i = tid; i < IN_DIM_ * OUT_DIM_; i += 256) ((float*)Ws)[i] = Wfc[i];
    __syncthreads();

    int lane = tid & 63;
    int slot = tid >> 6;
    float wa = w_attn[lane];

    int row0 = blockIdx.x * rows_per_block;
    int row_end = row0 + rows_per_block;
    if (row_end > NS_) row_end = NS_;

    for (int r = row0 + slot; r < row_end; r += 4) {
        const float4* hrow = (const float4*)(h + (size_t)r * IN_DIM_);
        float acc = 0.0f;
#pragma unroll
        for (int k4 = 0; k4 < IN_DIM_ / 4; ++k4) {
            float4 hv = hrow[k4];
            acc = fmaf(hv.x, Ws[k4 * 4 + 0][lane], acc);
            acc = fmaf(hv.y, Ws[k4 * 4 + 1][lane], acc);
            acc = fmaf(hv.z, Ws[k4 * 4 + 2][lane], acc);
            acc = fmaf(hv.w, Ws[k4 * 4 + 3][lane], acc);
        }
        z16[(size_t)r * OUT_DIM_ + lane] = __float2half(acc);

        float tv = acc * wa;
#pragma unroll
        for (int off = 32; off > 0; off >>= 1) tv += __shfl_down(tv, off, 64);
        if (lane == 0) t[r] = tv;
    }
}

// One block per slab of edges: LDS histogram by bucket (dst>>6), LDS scan,
// scatter (ev, src|dstlo) into slab-local bucket-sorted layout. All global
// writes stay inside this block's contiguous slab window -> dense writeback.
__global__ __launch_bounds__(256) void partition_kernel(const float* __restrict__ weight,
                                                        const int* __restrict__ src,
                                                        const int* __restrict__ dst,
                                                        const float* __restrict__ t,
                                                        int* __restrict__ offs_g,
                                                        int2* __restrict__ edata,
                                                        int E, int slab_e) {
    __shared__ int hist[NBP];
    __shared__ int scanv[NBP];
    __shared__ int part[256];
    __shared__ int cur[NB];
    int tid = threadIdx.x;
    int s = blockIdx.x;
    int e0 = s * slab_e;
    int e1 = e0 + slab_e; if (e1 > E) e1 = E;
    int cnt = e1 - e0;

    for (int i = tid; i < NBP; i += 256) hist[i] = 0;
    __syncthreads();
    for (int i = tid; i < cnt; i += 256) {
        atomicAdd(&hist[dst[e0 + i] >> 6], 1);
    }
    __syncthreads();

    // exclusive scan of hist[0..NB) -> scanv; scanv[NB] = cnt
    int c0 = tid * 4;
    int sum = 0;
#pragma unroll
    for (int k = 0; k < 4; ++k) { int idx = c0 + k; if (idx < NB) sum += hist[idx]; }
    part[tid] = sum;
    __syncthreads();
    for (int off = 1; off < 256; off <<= 1) {
        int v = (tid >= off) ? part[tid - off] : 0;
        __syncthreads();
        part[tid] += v;
        __syncthreads();
    }
    int run = (tid == 0) ? 0 : part[tid - 1];
#pragma unroll
    for (int k = 0; k < 4; ++k) {
        int idx = c0 + k;
        if (idx < NB) { scanv[idx] = run; run += hist[idx]; }
    }
    if (tid == 255) scanv[NB] = run;  // == cnt
    __syncthreads();

    for (int i = tid; i < NBP; i += 256) {
        offs_g[s * NBP + i] = scanv[i];
        if (i < NB) cur[i] = scanv[i];
    }
    __syncthreads();

    for (int i = tid; i < cnt; i += 256) {
        int e = e0 + i;
        int sr = src[e];
        int d = dst[e];
        float ev = weight[e] * leaky01(t[sr]);
        int b = d >> 6;
        int pos = atomicAdd(&cur[b], 1);
        edata[e0 + pos] = make_int2(__float_as_int(ev), sr | ((d & 63) << 16));
    }
}

// One block per bucket (64 dsts): gather this bucket's segments from all slabs
// into LDS, counting-sort by dst, then per-wave softmax + z-gather accumulate.
__global__ __launch_bounds__(512) void aggregate_kernel(const int* __restrict__ offs_g,
                                                        const int2* __restrict__ edata,
                                                        const __half* __restrict__ z16,
                                                        float* __restrict__ out,
                                                        int slab_e) {
    __shared__ int2 ebuf[CAP];
    __shared__ int2 sbuf[CAP];
    __shared__ int soff[NSLAB];
    __shared__ int scnt[NSLAB];
    __shared__ int segbase[NSLAB + 1];
    __shared__ int dcnt[64];
    __shared__ int dbase[65];
    __shared__ int dcur[64];

    int b = blockIdx.x;
    int tid = threadIdx.x;

    if (tid < NSLAB) {
        int o0 = offs_g[tid * NBP + b];
        int o1 = offs_g[tid * NBP + b + 1];
        soff[tid] = o0;
        scnt[tid] = o1 - o0;
    }
    if (tid < 64) dcnt[tid] = 0;
    __syncthreads();

    // exclusive scan of scnt -> segbase (in-place Hillis-Steele on scnt)
    for (int off = 1; off < NSLAB; off <<= 1) {
        int v = 0;
        if (tid < NSLAB && tid >= off) v = scnt[tid - off];
        __syncthreads();
        if (tid < NSLAB) scnt[tid] += v;
        __syncthreads();
    }
    if (tid < NSLAB) segbase[tid + 1] = scnt[tid];
    if (tid == 0) segbase[0] = 0;
    __syncthreads();

    int total = segbase[NSLAB];
    if (total > CAP) total = CAP;  // statistically impossible; avoid corruption

    // copy segments: 64 groups of 8 lanes, each group walks slabs g, g+64, ...
    int gid = tid >> 3, lane8 = tid & 7;
    for (int s = gid; s < NSLAB; s += 64) {
        int base = segbase[s];
        int len = segbase[s + 1] - base;
        int so = soff[s];
        for (int j = lane8; j < len; j += 8) {
            int p = base + j;
            if (p < CAP) ebuf[p] = edata[s * slab_e + so + j];
        }
    }
    __syncthreads();

    // histogram by dst-within-bucket
    for (int k = tid; k < total; k += 512) {
        atomicAdd(&dcnt[(ebuf[k].y >> 16) & 63], 1);
    }
    __syncthreads();
    if (tid < 64) {
        int v = dcnt[tid];
        int incl = v;
#pragma unroll
        for (int off = 1; off < 64; off <<= 1) {
            int u = __shfl_up(incl, off, 64);
            if (tid >= off) incl += u;
        }
        dbase[tid + 1] = incl;
        dcur[tid] = incl - v;
        if (tid == 0) dbase[0] = 0;
    }
    __syncthreads();

    // counting-sort into sbuf
    for (int k = tid; k < total; k += 512) {
        int2 e = ebuf[k];
        int d6 = (e.y >> 16) & 63;
        int p = atomicAdd(&dcur[d6], 1);
        sbuf[p] = e;
    }
    __syncthreads();

    // aggregate: 8 waves x 8 dsts each
    int wv = tid >> 6;
    int lane = tid & 63;
    for (int q = 0; q < 8; ++q) {
        int d6 = wv * 8 + q;
        int d = b * 64 + d6;
        if (d >= NW_) continue;
        int a0 = dbase[d6];
        int n = dbase[d6 + 1] - a0;
        float r = 0.0f;
        if (n > 0) {
            float mx = -INFINITY;
            for (int i = lane; i < n; i += 64)
                mx = fmaxf(mx, __int_as_float(sbuf[a0 + i].x));
#pragma unroll
            for (int off = 32; off > 0; off >>= 1) mx = fmaxf(mx, __shfl_xor(mx, off, 64));
            float den = 0.0f;
            for (int i = lane; i < n; i += 64)
                den += __expf(__int_as_float(sbuf[a0 + i].x) - mx);
#pragma unroll
            for (int off = 32; off > 0; off >>= 1) den += __shfl_xor(den, off, 64);

            float acc0 = 0.0f, acc1 = 0.0f, acc2 = 0.0f, acc3 = 0.0f;
            int j = 0;
            for (; j + 4 <= n; j += 4) {
                int2 e0 = sbuf[a0 + j], e1 = sbuf[a0 + j + 1];
                int2 e2 = sbuf[a0 + j + 2], e3 = sbuf[a0 + j + 3];
                acc0 = fmaf(__expf(__int_as_float(e0.x) - mx),
                            __half2float(z16[(e0.y & 0xFFFF) * OUT_DIM_ + lane]), acc0);
                acc1 = fmaf(__expf(__int_as_float(e1.x) - mx),
                            __half2float(z16[(e1.y & 0xFFFF) * OUT_DIM_ + lane]), acc1);
                acc2 = fmaf(__expf(__int_as_float(e2.x) - mx),
                            __half2float(z16[(e2.y & 0xFFFF) * OUT_DIM_ + lane]), acc2);
                acc3 = fmaf(__expf(__int_as_float(e3.x) - mx),
                            __half2float(z16[(e3.y & 0xFFFF) * OUT_DIM_ + lane]), acc3);
            }
            for (; j < n; ++j) {
                int2 e = sbuf[a0 + j];
                acc0 = fmaf(__expf(__int_as_float(e.x) - mx),
                            __half2float(z16[(e.y & 0xFFFF) * OUT_DIM_ + lane]), acc0);
            }
            r = (acc0 + acc1 + acc2 + acc3) / den;
        }
        out[(size_t)d * OUT_DIM_ + lane] = r;
    }
}

extern "C" void kernel_launch(void* const* d_in, const int* in_sizes, int n_in,
                              void* d_out, int out_size, void* d_ws, size_t ws_size,
                              hipStream_t stream) {
    const float* h      = (const float*)d_in[0];
    const float* Wfc    = (const float*)d_in[1];
    const float* w_attn = (const float*)d_in[2];
    const float* weight = (const float*)d_in[3];
    const int*   src    = (const int*)d_in[4];
    const int*   dst    = (const int*)d_in[5];
    int E = in_sizes[3];
    float* out = (float*)d_out;

    int slab_e = (E + NSLAB - 1) / NSLAB;  // 6250 for E=1.6M

    // workspace: edata (8B-aligned at base) | z16 | t | offs
    int2*   edata = (int2*)d_ws;                                   // E
    __half* z16   = (__half*)(edata + (size_t)E);                  // NS*64
    float*  t     = (float*)(z16 + (size_t)NS_ * OUT_DIM_);        // NS
    int*    offs  = (int*)(t + NS_);                               // NSLAB*NBP

    const int rows_per_block = 32;
    fc_kernel<<<(NS_ + rows_per_block - 1) / rows_per_block, 256, 0, stream>>>(
        h, Wfc, w_attn, z16, t, rows_per_block);

    partition_kernel<<<NSLAB, 256, 0, stream>>>(weight, src, dst, t, offs, edata, E, slab_e);

    aggregate_kernel<<<NB, 512, 0, stream>>>(offs, edata, z16, out, slab_e);
}

// Round 5
// 153.081 us; speedup vs baseline: 3.8401x; 1.1492x over previous
//
#include <hip/hip_runtime.h>
#include <hip/hip_fp16.h>
#include <math.h>

#define NS_ 50000
#define NW_ 50000
#define IN_DIM_ 128
#define OUT_DIM_ 64

#define NSLAB 256          // partition slabs (blocks)
#define NB 782             // buckets = ceil(NW/64), bucket = dst >> 6
#define CAP 2816           // LDS edge capacity per bucket (mean 2048, +17 sigma)

__device__ inline float leaky01(float x) { return x > 0.0f ? x : 0.01f * x; }

// monotone unsigned key: float order == unsigned key order
__device__ inline unsigned fkey(int iv) {
    return (iv < 0) ? ~((unsigned)iv) : (((unsigned)iv) | 0x80000000u);
}
__device__ inline float funkey(unsigned k) {
    unsigned u = (k & 0x80000000u) ? (k & 0x7fffffffu) : ~k;
    return __int_as_float((int)u);
}

// z = h @ W_fc (fp16 out), fused t[row] = sum_c z[row][c] * w_attn[c]
__global__ __launch_bounds__(256) void fc_kernel(const float* __restrict__ h,
                                                 const float* __restrict__ Wfc,
                                                 const float* __restrict__ w_attn,
                                                 __half* __restrict__ z16,
                                                 float* __restrict__ t,
                                                 int rows_per_block) {
    __shared__ float Ws[IN_DIM_][OUT_DIM_];
    int tid = threadIdx.x;
    for (int i = tid; i < IN_DIM_ * OUT_DIM_; i += 256) ((float*)Ws)[i] = Wfc[i];
    __syncthreads();

    int lane = tid & 63;
    int slot = tid >> 6;
    float wa = w_attn[lane];

    int row0 = blockIdx.x * rows_per_block;
    int row_end = row0 + rows_per_block;
    if (row_end > NS_) row_end = NS_;

    for (int r = row0 + slot; r < row_end; r += 4) {
        const float4* hrow = (const float4*)(h + (size_t)r * IN_DIM_);
        float acc = 0.0f;
#pragma unroll
        for (int k4 = 0; k4 < IN_DIM_ / 4; ++k4) {
            float4 hv = hrow[k4];
            acc = fmaf(hv.x, Ws[k4 * 4 + 0][lane], acc);
            acc = fmaf(hv.y, Ws[k4 * 4 + 1][lane], acc);
            acc = fmaf(hv.z, Ws[k4 * 4 + 2][lane], acc);
            acc = fmaf(hv.w, Ws[k4 * 4 + 3][lane], acc);
        }
        z16[(size_t)r * OUT_DIM_ + lane] = __float2half(acc);

        float tv = acc * wa;
#pragma unroll
        for (int off = 32; off > 0; off >>= 1) tv += __shfl_down(tv, off, 64);
        if (lane == 0) t[r] = tv;
    }
}

// One 1024-thread block per slab: LDS histogram by bucket (dst>>6), LDS scan,
// scatter (ev, src|dstlo) into slab-local bucket-sorted layout. Metadata is
// written TRANSPOSED (cntT[b][s], offT[b][s]) so aggregate reads it coalesced.
__global__ __launch_bounds__(1024) void partition_kernel(const float* __restrict__ weight,
                                                         const int* __restrict__ src,
                                                         const int* __restrict__ dst,
                                                         const float* __restrict__ t,
                                                         int* __restrict__ cntT,
                                                         int* __restrict__ offT,
                                                         int2* __restrict__ edata,
                                                         int E, int slab_e) {
    __shared__ int hist[NB];
    __shared__ int excl[NB];
    __shared__ int part[1024];
    __shared__ int cur[NB];
    int tid = threadIdx.x;
    int s = blockIdx.x;
    int e0 = s * slab_e;
    int e1 = e0 + slab_e; if (e1 > E) e1 = E;
    int cnt = e1 - e0;

    for (int i = tid; i < NB; i += 1024) hist[i] = 0;
    __syncthreads();
    for (int i = tid; i < cnt; i += 1024) {
        atomicAdd(&hist[dst[e0 + i] >> 6], 1);
    }
    __syncthreads();

    // inclusive Hillis-Steele over 1024 (NB=782 padded with 0)
    int hv = (tid < NB) ? hist[tid] : 0;
    part[tid] = hv;
    __syncthreads();
#pragma unroll
    for (int off = 1; off < 1024; off <<= 1) {
        int v = (tid >= off) ? part[tid - off] : 0;
        __syncthreads();
        part[tid] += v;
        __syncthreads();
    }
    if (tid < NB) {
        int ex = part[tid] - hv;   // exclusive
        excl[tid] = ex;
        cur[tid] = ex;
        cntT[tid * NSLAB + s] = hv;
        offT[tid * NSLAB + s] = ex;
    }
    __syncthreads();

    for (int i = tid; i < cnt; i += 1024) {
        int e = e0 + i;
        int sr = src[e];
        int d = dst[e];
        float ev = weight[e] * leaky01(t[sr]);
        int b = d >> 6;
        int pos = atomicAdd(&cur[b], 1);
        edata[e0 + pos] = make_int2(__float_as_int(ev), sr | ((d & 63) << 16));
    }
}

// One 512-thread block per bucket (64 dsts):
//  pass1: gather bucket segments global->LDS, per-dst count + max (LDS atomics)
//  pass2: ex = exp(ev-mx) (stored in place), den += ex, perm index counting-sort
//  aggregate: per wave x 8 dsts, pure 8-unrolled gather-FMA over z16
__global__ __launch_bounds__(512) void aggregate_kernel(const int* __restrict__ cntT,
                                                        const int* __restrict__ offT,
                                                        int2* __restrict__ edata,
                                                        const __half* __restrict__ z16,
                                                        float* __restrict__ out,
                                                        int slab_e) {
    __shared__ int2 sbuf[CAP];            // 22528 B
    __shared__ unsigned short perm[CAP];  // 5632 B
    __shared__ int soff[NSLAB];
    __shared__ int seg[NSLAB + 1];
    __shared__ int part[NSLAB];
    __shared__ unsigned dmaxkey[64];
    __shared__ float dmx[64];
    __shared__ float dden[64];
    __shared__ int dcnt[64];
    __shared__ int dbase[65];
    __shared__ int dcur[64];

    int b = blockIdx.x;
    int tid = threadIdx.x;

    int myc = 0;
    if (tid < NSLAB) {
        myc = cntT[b * NSLAB + tid];      // coalesced
        soff[tid] = offT[b * NSLAB + tid];
        part[tid] = myc;
    }
    if (tid < 64) {
        dcnt[tid] = 0;
        dmaxkey[tid] = 0u;
        dden[tid] = 0.0f;
    }
    __syncthreads();

    // exclusive scan of per-slab counts -> seg
#pragma unroll
    for (int off = 1; off < NSLAB; off <<= 1) {
        int v = (tid < NSLAB && tid >= off) ? part[tid - off] : 0;
        __syncthreads();
        if (tid < NSLAB) part[tid] += v;
        __syncthreads();
    }
    if (tid < NSLAB) seg[tid + 1] = part[tid];
    if (tid == 0) seg[0] = 0;
    __syncthreads();

    int total = seg[NSLAB];
    if (total > CAP) total = CAP;  // statistically impossible; avoid corruption

    // pass1: copy segments + per-dst count/max. 64 groups x 8 lanes.
    int gid = tid >> 3, l8 = tid & 7;
    for (int s = gid; s < NSLAB; s += 64) {
        int base = seg[s];
        int len = seg[s + 1] - base;
        int so = soff[s];
        for (int j = l8; j < len; j += 8) {
            int p = base + j;
            if (p < CAP) {
                int2 e = edata[(size_t)s * slab_e + so + j];
                sbuf[p] = e;
                int d6 = (e.y >> 16) & 63;
                atomicAdd(&dcnt[d6], 1);
                atomicMax(&dmaxkey[d6], fkey(e.x));
            }
        }
    }
    __syncthreads();

    if (tid < 64) {
        dmx[tid] = funkey(dmaxkey[tid]);
        int v = dcnt[tid];
        int incl = v;
#pragma unroll
        for (int off = 1; off < 64; off <<= 1) {
            int u = __shfl_up(incl, off, 64);
            if (tid >= off) incl += u;
        }
        dbase[tid + 1] = incl;
        dcur[tid] = incl - v;
        if (tid == 0) dbase[0] = 0;
    }
    __syncthreads();

    // pass2: ex in place, den accumulate, perm counting-sort
    for (int k = tid; k < total; k += 512) {
        int2 e = sbuf[k];
        int d6 = (e.y >> 16) & 63;
        float ex = __expf(__int_as_float(e.x) - dmx[d6]);
        atomicAdd(&dden[d6], ex);
        int pos = atomicAdd(&dcur[d6], 1);
        perm[pos] = (unsigned short)k;
        sbuf[k].x = __float_as_int(ex);
    }
    __syncthreads();

    // aggregate: 8 waves x 8 dsts each, 8-unrolled gather loop
    int wv = tid >> 6;
    int lane = tid & 63;
    for (int q = 0; q < 8; ++q) {
        int d6 = wv * 8 + q;
        int d = b * 64 + d6;
        if (d >= NW_) continue;
        int a0 = dbase[d6];
        int n = dbase[d6 + 1] - a0;
        float r = 0.0f;
        if (n > 0) {
            float invden = 1.0f / dden[d6];
            float a0f = 0.f, a1f = 0.f, a2f = 0.f, a3f = 0.f;
            float a4f = 0.f, a5f = 0.f, a6f = 0.f, a7f = 0.f;
            int j = 0;
            for (; j + 8 <= n; j += 8) {
                int k0 = perm[a0 + j + 0], k1 = perm[a0 + j + 1];
                int k2 = perm[a0 + j + 2], k3 = perm[a0 + j + 3];
                int k4 = perm[a0 + j + 4], k5 = perm[a0 + j + 5];
                int k6 = perm[a0 + j + 6], k7 = perm[a0 + j + 7];
                int2 e0 = sbuf[k0], e1 = sbuf[k1], e2 = sbuf[k2], e3 = sbuf[k3];
                int2 e4 = sbuf[k4], e5 = sbuf[k5], e6 = sbuf[k6], e7 = sbuf[k7];
                a0f = fmaf(__int_as_float(e0.x), __half2float(z16[(e0.y & 0xFFFF) * OUT_DIM_ + lane]), a0f);
                a1f = fmaf(__int_as_float(e1.x), __half2float(z16[(e1.y & 0xFFFF) * OUT_DIM_ + lane]), a1f);
                a2f = fmaf(__int_as_float(e2.x), __half2float(z16[(e2.y & 0xFFFF) * OUT_DIM_ + lane]), a2f);
                a3f = fmaf(__int_as_float(e3.x), __half2float(z16[(e3.y & 0xFFFF) * OUT_DIM_ + lane]), a3f);
                a4f = fmaf(__int_as_float(e4.x), __half2float(z16[(e4.y & 0xFFFF) * OUT_DIM_ + lane]), a4f);
                a5f = fmaf(__int_as_float(e5.x), __half2float(z16[(e5.y & 0xFFFF) * OUT_DIM_ + lane]), a5f);
                a6f = fmaf(__int_as_float(e6.x), __half2float(z16[(e6.y & 0xFFFF) * OUT_DIM_ + lane]), a6f);
                a7f = fmaf(__int_as_float(e7.x), __half2float(z16[(e7.y & 0xFFFF) * OUT_DIM_ + lane]), a7f);
            }
            for (; j < n; ++j) {
                int kk = perm[a0 + j];
                int2 e = sbuf[kk];
                a0f = fmaf(__int_as_float(e.x), __half2float(z16[(e.y & 0xFFFF) * OUT_DIM_ + lane]), a0f);
            }
            r = ((a0f + a1f) + (a2f + a3f) + ((a4f + a5f) + (a6f + a7f))) * invden;
        }
        out[(size_t)d * OUT_DIM_ + lane] = r;
    }
}

extern "C" void kernel_launch(void* const* d_in, const int* in_sizes, int n_in,
                              void* d_out, int out_size, void* d_ws, size_t ws_size,
                              hipStream_t stream) {
    const float* h      = (const float*)d_in[0];
    const float* Wfc    = (const float*)d_in[1];
    const float* w_attn = (const float*)d_in[2];
    const float* weight = (const float*)d_in[3];
    const int*   src    = (const int*)d_in[4];
    const int*   dst    = (const int*)d_in[5];
    int E = in_sizes[3];
    float* out = (float*)d_out;

    int slab_e = (E + NSLAB - 1) / NSLAB;  // 6250 for E=1.6M

    // workspace: edata (8B-aligned) | z16 | t | cntT | offT
    int2*   edata = (int2*)d_ws;                                   // E
    __half* z16   = (__half*)(edata + (size_t)E);                  // NS*64
    float*  t     = (float*)(z16 + (size_t)NS_ * OUT_DIM_);        // NS
    int*    cntT  = (int*)(t + NS_);                               // NB*NSLAB
    int*    offT  = cntT + NB * NSLAB;                             // NB*NSLAB

    const int rows_per_block = 32;
    fc_kernel<<<(NS_ + rows_per_block - 1) / rows_per_block, 256, 0, stream>>>(
        h, Wfc, w_attn, z16, t, rows_per_block);

    partition_kernel<<<NSLAB, 1024, 0, stream>>>(weight, src, dst, t, cntT, offT, edata, E, slab_e);

    aggregate_kernel<<<NB, 512, 0, stream>>>(cntT, offT, edata, z16, out, slab_e);
}

// Round 6
// 128.765 us; speedup vs baseline: 4.5653x; 1.1888x over previous
//
#include <hip/hip_runtime.h>
#include <hip/hip_fp16.h>
#include <math.h>

#define NS_ 50000
#define NW_ 50000
#define IN_DIM_ 128
#define OUT_DIM_ 64

#define NSLAB 256          // partition slabs (blocks)
#define NB 782             // buckets = ceil(NW/64), bucket = dst >> 6
#define CAP 2816           // LDS edge capacity per bucket (mean 2048, +17 sigma)

__device__ inline float leaky01(float x) { return x > 0.0f ? x : 0.01f * x; }

// monotone unsigned key: float order == unsigned key order
__device__ inline unsigned fkey(int iv) {
    return (iv < 0) ? ~((unsigned)iv) : (((unsigned)iv) | 0x80000000u);
}
__device__ inline float funkey(unsigned k) {
    unsigned u = (k & 0x80000000u) ? (k & 0x7fffffffu) : ~k;
    return __int_as_float((int)u);
}

// z = h @ W_fc (fp16 out), fused t[row] = sum_c z[row][c] * w_attn[c]
// lane = output column, W[:,lane] in 128 VGPRs; h staged in LDS, broadcast-read;
// 2 rows x 4 accumulators = 8 independent FMA chains.
__global__ __launch_bounds__(256) void fc_kernel(const float* __restrict__ h,
                                                 const float* __restrict__ Wfc,
                                                 const float* __restrict__ w_attn,
                                                 __half* __restrict__ z16,
                                                 float* __restrict__ t) {
    __shared__ float hs[64 * IN_DIM_];   // 32 KB
    int tid = threadIdx.x;
    int lane = tid & 63;
    int wv = tid >> 6;

    float Wc[IN_DIM_];
#pragma unroll
    for (int k = 0; k < IN_DIM_; ++k) Wc[k] = Wfc[k * OUT_DIM_ + lane];  // coalesced
    float wa = w_attn[lane];

    int row0 = blockIdx.x * 64;
    int nrows = NS_ - row0; if (nrows > 64) nrows = 64;

    const float4* hg = (const float4*)(h + (size_t)row0 * IN_DIM_);
    float4* hs4 = (float4*)hs;
    int nv = nrows * (IN_DIM_ / 4);
    for (int i = tid; i < nv; i += 256) hs4[i] = hg[i];
    __syncthreads();

    int rend = wv * 16 + 16; if (rend > nrows) rend = nrows;
    for (int r = wv * 16; r < rend; r += 2) {
        bool two = (r + 1 < rend);
        const float4* h0 = (const float4*)(hs + r * IN_DIM_);
        const float4* h1 = (const float4*)(hs + (two ? r + 1 : r) * IN_DIM_);
        float a0 = 0, a1 = 0, a2 = 0, a3 = 0;
        float b0 = 0, b1 = 0, b2 = 0, b3 = 0;
#pragma unroll
        for (int k4 = 0; k4 < IN_DIM_ / 4; ++k4) {
            float4 u = h0[k4];   // wave-uniform LDS broadcast
            float4 v = h1[k4];
            a0 = fmaf(u.x, Wc[4 * k4 + 0], a0);
            a1 = fmaf(u.y, Wc[4 * k4 + 1], a1);
            a2 = fmaf(u.z, Wc[4 * k4 + 2], a2);
            a3 = fmaf(u.w, Wc[4 * k4 + 3], a3);
            b0 = fmaf(v.x, Wc[4 * k4 + 0], b0);
            b1 = fmaf(v.y, Wc[4 * k4 + 1], b1);
            b2 = fmaf(v.z, Wc[4 * k4 + 2], b2);
            b3 = fmaf(v.w, Wc[4 * k4 + 3], b3);
        }
        float za = (a0 + a1) + (a2 + a3);
        float zb = (b0 + b1) + (b2 + b3);
        z16[(size_t)(row0 + r) * OUT_DIM_ + lane] = __float2half(za);
        if (two) z16[(size_t)(row0 + r + 1) * OUT_DIM_ + lane] = __float2half(zb);
        float ta = za * wa, tb = zb * wa;
#pragma unroll
        for (int off = 32; off > 0; off >>= 1) {
            ta += __shfl_down(ta, off, 64);
            tb += __shfl_down(tb, off, 64);
        }
        if (lane == 0) {
            t[row0 + r] = ta;
            if (two) t[row0 + r + 1] = tb;
        }
    }
}

// One 1024-thread block per slab: LDS histogram by bucket (dst>>6), LDS scan,
// scatter (ev, src|dstlo) into slab-local bucket-sorted layout. Metadata is
// written TRANSPOSED (cntT[b][s], offT[b][s]) so aggregate reads it coalesced.
__global__ __launch_bounds__(1024) void partition_kernel(const float* __restrict__ weight,
                                                         const int* __restrict__ src,
                                                         const int* __restrict__ dst,
                                                         const float* __restrict__ t,
                                                         int* __restrict__ cntT,
                                                         int* __restrict__ offT,
                                                         int2* __restrict__ edata,
                                                         int E, int slab_e) {
    __shared__ int hist[NB];
    __shared__ int part[1024];
    __shared__ int cur[NB];
    int tid = threadIdx.x;
    int s = blockIdx.x;
    int e0 = s * slab_e;
    int e1 = e0 + slab_e; if (e1 > E) e1 = E;
    int cnt = e1 - e0;

    for (int i = tid; i < NB; i += 1024) hist[i] = 0;
    __syncthreads();
    for (int i = tid; i < cnt; i += 1024) {
        atomicAdd(&hist[dst[e0 + i] >> 6], 1);
    }
    __syncthreads();

    // inclusive Hillis-Steele over 1024 (NB=782 padded with 0)
    int hv = (tid < NB) ? hist[tid] : 0;
    part[tid] = hv;
    __syncthreads();
#pragma unroll
    for (int off = 1; off < 1024; off <<= 1) {
        int v = (tid >= off) ? part[tid - off] : 0;
        __syncthreads();
        part[tid] += v;
        __syncthreads();
    }
    if (tid < NB) {
        int ex = part[tid] - hv;   // exclusive
        cur[tid] = ex;
        cntT[tid * NSLAB + s] = hv;
        offT[tid * NSLAB + s] = ex;
    }
    __syncthreads();

    for (int i = tid; i < cnt; i += 1024) {
        int e = e0 + i;
        int sr = src[e];
        int d = dst[e];
        float ev = weight[e] * leaky01(t[sr]);
        int b = d >> 6;
        int pos = atomicAdd(&cur[b], 1);
        edata[e0 + pos] = make_int2(__float_as_int(ev), sr | ((d & 63) << 16));
    }
}

// One 512-thread block per bucket (64 dsts):
//  pass1: gather bucket segments global->LDS, per-dst count + max (LDS atomics)
//  pass2: ex = exp(ev-mx) (stored in place), den += ex, perm index counting-sort
//  aggregate: per wave x 8 dsts, pure 8-unrolled gather-FMA over z16
__global__ __launch_bounds__(512) void aggregate_kernel(const int* __restrict__ cntT,
                                                        const int* __restrict__ offT,
                                                        int2* __restrict__ edata,
                                                        const __half* __restrict__ z16,
                                                        float* __restrict__ out,
                                                        int slab_e) {
    __shared__ int2 sbuf[CAP];            // 22528 B
    __shared__ unsigned short perm[CAP];  // 5632 B
    __shared__ int soff[NSLAB];
    __shared__ int seg[NSLAB + 1];
    __shared__ int part[NSLAB];
    __shared__ unsigned dmaxkey[64];
    __shared__ float dmx[64];
    __shared__ float dden[64];
    __shared__ int dcnt[64];
    __shared__ int dbase[65];
    __shared__ int dcur[64];

    int b = blockIdx.x;
    int tid = threadIdx.x;

    int myc = 0;
    if (tid < NSLAB) {
        myc = cntT[b * NSLAB + tid];      // coalesced
        soff[tid] = offT[b * NSLAB + tid];
        part[tid] = myc;
    }
    if (tid < 64) {
        dcnt[tid] = 0;
        dmaxkey[tid] = 0u;
        dden[tid] = 0.0f;
    }
    __syncthreads();

    // exclusive scan of per-slab counts -> seg
#pragma unroll
    for (int off = 1; off < NSLAB; off <<= 1) {
        int v = (tid < NSLAB && tid >= off) ? part[tid - off] : 0;
        __syncthreads();
        if (tid < NSLAB) part[tid] += v;
        __syncthreads();
    }
    if (tid < NSLAB) seg[tid + 1] = part[tid];
    if (tid == 0) seg[0] = 0;
    __syncthreads();

    int total = seg[NSLAB];
    if (total > CAP) total = CAP;  // statistically impossible; avoid corruption

    // pass1: copy segments + per-dst count/max. 64 groups x 8 lanes.
    int gid = tid >> 3, l8 = tid & 7;
    for (int s = gid; s < NSLAB; s += 64) {
        int base = seg[s];
        int len = seg[s + 1] - base;
        int so = soff[s];
        for (int j = l8; j < len; j += 8) {
            int p = base + j;
            if (p < CAP) {
                int2 e = edata[(size_t)s * slab_e + so + j];
                sbuf[p] = e;
                int d6 = (e.y >> 16) & 63;
                atomicAdd(&dcnt[d6], 1);
                atomicMax(&dmaxkey[d6], fkey(e.x));
            }
        }
    }
    __syncthreads();

    if (tid < 64) {
        dmx[tid] = funkey(dmaxkey[tid]);
        int v = dcnt[tid];
        int incl = v;
#pragma unroll
        for (int off = 1; off < 64; off <<= 1) {
            int u = __shfl_up(incl, off, 64);
            if (tid >= off) incl += u;
        }
        dbase[tid + 1] = incl;
        dcur[tid] = incl - v;
        if (tid == 0) dbase[0] = 0;
    }
    __syncthreads();

    // pass2: ex in place, den accumulate, perm counting-sort
    for (int k = tid; k < total; k += 512) {
        int2 e = sbuf[k];
        int d6 = (e.y >> 16) & 63;
        float ex = __expf(__int_as_float(e.x) - dmx[d6]);
        atomicAdd(&dden[d6], ex);
        int pos = atomicAdd(&dcur[d6], 1);
        perm[pos] = (unsigned short)k;
        sbuf[k].x = __float_as_int(ex);
    }
    __syncthreads();

    // aggregate: 8 waves x 8 dsts each, 8-unrolled gather loop
    int wv = tid >> 6;
    int lane = tid & 63;
    for (int q = 0; q < 8; ++q) {
        int d6 = wv * 8 + q;
        int d = b * 64 + d6;
        if (d >= NW_) continue;
        int a0 = dbase[d6];
        int n = dbase[d6 + 1] - a0;
        float r = 0.0f;
        if (n > 0) {
            float invden = 1.0f / dden[d6];
            float a0f = 0.f, a1f = 0.f, a2f = 0.f, a3f = 0.f;
            float a4f = 0.f, a5f = 0.f, a6f = 0.f, a7f = 0.f;
            int j = 0;
            for (; j + 8 <= n; j += 8) {
                int k0 = perm[a0 + j + 0], k1 = perm[a0 + j + 1];
                int k2 = perm[a0 + j + 2], k3 = perm[a0 + j + 3];
                int k4 = perm[a0 + j + 4], k5 = perm[a0 + j + 5];
                int k6 = perm[a0 + j + 6], k7 = perm[a0 + j + 7];
                int2 e0 = sbuf[k0], e1 = sbuf[k1], e2 = sbuf[k2], e3 = sbuf[k3];
                int2 e4 = sbuf[k4], e5 = sbuf[k5], e6 = sbuf[k6], e7 = sbuf[k7];
                a0f = fmaf(__int_as_float(e0.x), __half2float(z16[(e0.y & 0xFFFF) * OUT_DIM_ + lane]), a0f);
                a1f = fmaf(__int_as_float(e1.x), __half2float(z16[(e1.y & 0xFFFF) * OUT_DIM_ + lane]), a1f);
                a2f = fmaf(__int_as_float(e2.x), __half2float(z16[(e2.y & 0xFFFF) * OUT_DIM_ + lane]), a2f);
                a3f = fmaf(__int_as_float(e3.x), __half2float(z16[(e3.y & 0xFFFF) * OUT_DIM_ + lane]), a3f);
                a4f = fmaf(__int_as_float(e4.x), __half2float(z16[(e4.y & 0xFFFF) * OUT_DIM_ + lane]), a4f);
                a5f = fmaf(__int_as_float(e5.x), __half2float(z16[(e5.y & 0xFFFF) * OUT_DIM_ + lane]), a5f);
                a6f = fmaf(__int_as_float(e6.x), __half2float(z16[(e6.y & 0xFFFF) * OUT_DIM_ + lane]), a6f);
                a7f = fmaf(__int_as_float(e7.x), __half2float(z16[(e7.y & 0xFFFF) * OUT_DIM_ + lane]), a7f);
            }
            for (; j < n; ++j) {
                int kk = perm[a0 + j];
                int2 e = sbuf[kk];
                a0f = fmaf(__int_as_float(e.x), __half2float(z16[(e.y & 0xFFFF) * OUT_DIM_ + lane]), a0f);
            }
            r = ((a0f + a1f) + (a2f + a3f) + ((a4f + a5f) + (a6f + a7f))) * invden;
        }
        out[(size_t)d * OUT_DIM_ + lane] = r;
    }
}

extern "C" void kernel_launch(void* const* d_in, const int* in_sizes, int n_in,
                              void* d_out, int out_size, void* d_ws, size_t ws_size,
                              hipStream_t stream) {
    const float* h      = (const float*)d_in[0];
    const float* Wfc    = (const float*)d_in[1];
    const float* w_attn = (const float*)d_in[2];
    const float* weight = (const float*)d_in[3];
    const int*   src    = (const int*)d_in[4];
    const int*   dst    = (const int*)d_in[5];
    int E = in_sizes[3];
    float* out = (float*)d_out;

    int slab_e = (E + NSLAB - 1) / NSLAB;  // 6250 for E=1.6M

    // workspace: edata (8B-aligned) | z16 | t | cntT | offT
    int2*   edata = (int2*)d_ws;                                   // E
    __half* z16   = (__half*)(edata + (size_t)E);                  // NS*64
    float*  t     = (float*)(z16 + (size_t)NS_ * OUT_DIM_);        // NS
    int*    cntT  = (int*)(t + NS_);                               // NB*NSLAB
    int*    offT  = cntT + NB * NSLAB;                             // NB*NSLAB

    fc_kernel<<<(NS_ + 63) / 64, 256, 0, stream>>>(h, Wfc, w_attn, z16, t);

    partition_kernel<<<NSLAB, 1024, 0, stream>>>(weight, src, dst, t, cntT, offT, edata, E, slab_e);

    aggregate_kernel<<<NB, 512, 0, stream>>>(cntT, offT, edata, z16, out, slab_e);
}